// Round 1
// baseline (229.815 us; speedup 1.0000x reference)
//
#include <hip/hip_runtime.h>

// ROIAlign: features (1, 256, 200, 200) f32, rois (512,4) f32 (y1,x1,y2,x2),
// img_size (2,) f32 = [800, 800]. Output (N, 256, 7, 7) f32.
// Each output cell = max over 2x2 subsamples of bilinear-interpolated features.

#define CCH 256
#define HF 200
#define WF 200
#define HOUT 7
#define WOUT 7
#define SPP 49   // 7*7

__global__ __launch_bounds__(256) void roialign_kernel(
    const float* __restrict__ features,  // (256, 200, 200)
    const float* __restrict__ rois,      // (N, 4)
    float* __restrict__ out,             // (N, 256, 7, 7) flat
    int total)
{
    int idx = blockIdx.x * blockDim.x + threadIdx.x;
    if (idx >= total) return;

    int s  = idx % SPP;
    int nc = idx / SPP;
    int c  = nc % CCH;
    int n  = nc / CCH;
    int ho = s / WOUT;
    int wo = s % WOUT;

    // r = rois * (fhw - 1) / (isz - 1)  ->  (roi * 199) / 799, matching ref order
    float r0 = (rois[n * 4 + 0] * 199.0f) / 799.0f;  // y1
    float r1 = (rois[n * 4 + 1] * 199.0f) / 799.0f;  // x1
    float r2 = (rois[n * 4 + 2] * 199.0f) / 799.0f;  // y2
    float r3 = (rois[n * 4 + 3] * 199.0f) / 799.0f;  // x2

    float h_step = (r2 - r0) / 14.0f;  // Hs = 7*2
    float w_step = (r3 - r1) / 14.0f;  // Ws = 7*2

    const float* fmap = features + (size_t)c * (HF * WF);

    float result = -INFINITY;

    #pragma unroll
    for (int a = 0; a < 2; ++a) {
        float yy = ((float)(2 * ho + a) + 0.5f) * h_step + r0;
        float yf = floorf(yy);
        int   iu = (int)yf;
        int   id = (int)ceilf(yy);   // ceil, NOT floor+1 (matches ref; avoids OOB)
        float fy = yy - yf;

        const float* rowu = fmap + (size_t)iu * WF;
        const float* rowd = fmap + (size_t)id * WF;

        #pragma unroll
        for (int b = 0; b < 2; ++b) {
            float xx = ((float)(2 * wo + b) + 0.5f) * w_step + r1;
            float xf = floorf(xx);
            int   il = (int)xf;
            int   ir = (int)ceilf(xx);
            float fx = xx - xf;

            float v_ul = rowu[il];
            float v_ur = rowu[ir];
            float v_dl = rowd[il];
            float v_dr = rowd[ir];

            float val = v_ul * (1.0f - fy) * (1.0f - fx)
                      + v_dl * fy         * (1.0f - fx)
                      + v_ur * (1.0f - fy) * fx
                      + v_dr * fy         * fx;

            result = fmaxf(result, val);
        }
    }

    out[idx] = result;
}

extern "C" void kernel_launch(void* const* d_in, const int* in_sizes, int n_in,
                              void* d_out, int out_size, void* d_ws, size_t ws_size,
                              hipStream_t stream) {
    const float* features = (const float*)d_in[0];  // (1, 256, 200, 200)
    const float* rois     = (const float*)d_in[1];  // (N, 4)
    // d_in[2] = img_size, constant [800, 800] — folded into the kernel math.
    float* out = (float*)d_out;

    int N = in_sizes[1] / 4;
    int total = N * CCH * SPP;

    int block = 256;
    int grid = (total + block - 1) / block;
    roialign_kernel<<<grid, block, 0, stream>>>(features, rois, out, total);
}

// Round 2
// 152.948 us; speedup vs baseline: 1.5026x; 1.5026x over previous
//
#include <hip/hip_runtime.h>

// ROIAlign: features (1, 256, 200, 200) f32, rois (N,4) f32 (y1,x1,y2,x2),
// img_size constant [800, 800]. Output (N, 256, 7, 7) f32.
//
// Strategy: transpose features to (H, W, C) in d_ws so that each bilinear tap
// for all 256 channels is a 1 KB contiguous read (perfect coalescing), then
// one block per (roi, ho) with 64 threads x float4 channels.

#define CCH 256
#define HF 200
#define WF 200
#define HOUT 7
#define WOUT 7
#define SPP 49

// ---------------- transpose (C,H,W) -> (H,W,C) ----------------
// grid: (HF, C/64, ceil(WF/64)); block: 256 threads; LDS 64x65 tile.
__global__ __launch_bounds__(256) void transpose_chw_hwc(
    const float* __restrict__ f,   // (C, H, W)
    float* __restrict__ ft)        // (H, W, C)
{
    __shared__ float tile[64][65];
    int h  = blockIdx.x;
    int cg = blockIdx.y;   // channel group of 64
    int wg = blockIdx.z;   // w group of 64

    int t  = threadIdx.x;
    int lw = t & 63;       // lane within 64
    int q  = t >> 6;       // 0..3

    // phase 1: read (c, w) coalesced along w
    #pragma unroll
    for (int i = 0; i < 16; ++i) {
        int c_local = q * 16 + i;
        int w = wg * 64 + lw;
        float v = 0.0f;
        if (w < WF) {
            v = f[(size_t)(cg * 64 + c_local) * (HF * WF) + (size_t)h * WF + w];
        }
        tile[c_local][lw] = v;
    }
    __syncthreads();

    // phase 2: write (w, c) coalesced along c
    #pragma unroll
    for (int i = 0; i < 16; ++i) {
        int w_local = q * 16 + i;
        int w = wg * 64 + w_local;
        if (w < WF) {
            ft[((size_t)h * WF + w) * CCH + cg * 64 + lw] = tile[lw][w_local];
        }
    }
}

// ---------------- main: block = (ho, n), 64 threads, 4 ch/thread ----------------
__global__ __launch_bounds__(64) void roialign_main(
    const float* __restrict__ ft,    // (H, W, C)
    const float* __restrict__ rois,  // (N, 4)
    float* __restrict__ out)         // (N, C, 7, 7)
{
    int ho = blockIdx.x;   // 0..6
    int n  = blockIdx.y;
    int c4 = (threadIdx.x) * 4;   // channel base for this thread

    // ROI params (uniform across block)
    float r0 = (rois[n * 4 + 0] * 199.0f) / 799.0f;
    float r1 = (rois[n * 4 + 1] * 199.0f) / 799.0f;
    float r2 = (rois[n * 4 + 2] * 199.0f) / 799.0f;
    float r3 = (rois[n * 4 + 3] * 199.0f) / 799.0f;
    float h_step = (r2 - r0) / 14.0f;
    float w_step = (r3 - r1) / 14.0f;

    float accx[WOUT], accy[WOUT], accz[WOUT], accw[WOUT];
    #pragma unroll
    for (int wo = 0; wo < WOUT; ++wo) {
        accx[wo] = -INFINITY; accy[wo] = -INFINITY;
        accz[wo] = -INFINITY; accw[wo] = -INFINITY;
    }

    #pragma unroll
    for (int a = 0; a < 2; ++a) {
        float yy = ((float)(2 * ho + a) + 0.5f) * h_step + r0;
        float yf = floorf(yy);
        int   iu = (int)yf;
        int   id = (int)ceilf(yy);
        float fy = yy - yf;

        const float* rowu = ft + (size_t)iu * (WF * CCH);
        const float* rowd = ft + (size_t)id * (WF * CCH);

        #pragma unroll
        for (int wo = 0; wo < WOUT; ++wo) {
            #pragma unroll
            for (int b = 0; b < 2; ++b) {
                float xx = ((float)(2 * wo + b) + 0.5f) * w_step + r1;
                float xf = floorf(xx);
                int   il = (int)xf;
                int   ir = (int)ceilf(xx);
                float fx = xx - xf;

                const float4 ul = *(const float4*)(rowu + (size_t)il * CCH + c4);
                const float4 ur = *(const float4*)(rowu + (size_t)ir * CCH + c4);
                const float4 dl = *(const float4*)(rowd + (size_t)il * CCH + c4);
                const float4 dr = *(const float4*)(rowd + (size_t)ir * CCH + c4);

                float w_ul = (1.0f - fy) * (1.0f - fx);
                float w_dl = fy * (1.0f - fx);
                float w_ur = (1.0f - fy) * fx;
                float w_dr = fy * fx;

                float vx = ul.x * w_ul + dl.x * w_dl + ur.x * w_ur + dr.x * w_dr;
                float vy = ul.y * w_ul + dl.y * w_dl + ur.y * w_ur + dr.y * w_dr;
                float vz = ul.z * w_ul + dl.z * w_dl + ur.z * w_ur + dr.z * w_dr;
                float vw = ul.w * w_ul + dl.w * w_dl + ur.w * w_ur + dr.w * w_dr;

                accx[wo] = fmaxf(accx[wo], vx);
                accy[wo] = fmaxf(accy[wo], vy);
                accz[wo] = fmaxf(accz[wo], vz);
                accw[wo] = fmaxf(accw[wo], vw);
            }
        }
    }

    // store: channel c row = out[(n*256 + c)*49 + ho*7 + wo]
    size_t base = ((size_t)n * CCH + c4) * SPP + ho * WOUT;
    #pragma unroll
    for (int wo = 0; wo < WOUT; ++wo) {
        out[base + 0 * SPP + wo] = accx[wo];
        out[base + 1 * SPP + wo] = accy[wo];
        out[base + 2 * SPP + wo] = accz[wo];
        out[base + 3 * SPP + wo] = accw[wo];
    }
}

// ---------------- fallback (round-0 kernel) if ws too small ----------------
__global__ __launch_bounds__(256) void roialign_fallback(
    const float* __restrict__ features,
    const float* __restrict__ rois,
    float* __restrict__ out,
    int total)
{
    int idx = blockIdx.x * blockDim.x + threadIdx.x;
    if (idx >= total) return;

    int s  = idx % SPP;
    int nc = idx / SPP;
    int c  = nc % CCH;
    int n  = nc / CCH;
    int ho = s / WOUT;
    int wo = s % WOUT;

    float r0 = (rois[n * 4 + 0] * 199.0f) / 799.0f;
    float r1 = (rois[n * 4 + 1] * 199.0f) / 799.0f;
    float r2 = (rois[n * 4 + 2] * 199.0f) / 799.0f;
    float r3 = (rois[n * 4 + 3] * 199.0f) / 799.0f;
    float h_step = (r2 - r0) / 14.0f;
    float w_step = (r3 - r1) / 14.0f;

    const float* fmap = features + (size_t)c * (HF * WF);
    float result = -INFINITY;

    #pragma unroll
    for (int a = 0; a < 2; ++a) {
        float yy = ((float)(2 * ho + a) + 0.5f) * h_step + r0;
        float yf = floorf(yy);
        int   iu = (int)yf;
        int   id = (int)ceilf(yy);
        float fy = yy - yf;
        const float* rowu = fmap + (size_t)iu * WF;
        const float* rowd = fmap + (size_t)id * WF;
        #pragma unroll
        for (int b = 0; b < 2; ++b) {
            float xx = ((float)(2 * wo + b) + 0.5f) * w_step + r1;
            float xf = floorf(xx);
            int   il = (int)xf;
            int   ir = (int)ceilf(xx);
            float fx = xx - xf;
            float val = rowu[il] * (1.0f - fy) * (1.0f - fx)
                      + rowd[il] * fy         * (1.0f - fx)
                      + rowu[ir] * (1.0f - fy) * fx
                      + rowd[ir] * fy         * fx;
            result = fmaxf(result, val);
        }
    }
    out[idx] = result;
}

extern "C" void kernel_launch(void* const* d_in, const int* in_sizes, int n_in,
                              void* d_out, int out_size, void* d_ws, size_t ws_size,
                              hipStream_t stream) {
    const float* features = (const float*)d_in[0];  // (1, 256, 200, 200)
    const float* rois     = (const float*)d_in[1];  // (N, 4)
    float* out = (float*)d_out;
    int N = in_sizes[1] / 4;

    const size_t need = (size_t)HF * WF * CCH * sizeof(float);  // 41 MB
    if (ws_size >= need) {
        float* ft = (float*)d_ws;
        dim3 tgrid(HF, CCH / 64, (WF + 63) / 64);
        transpose_chw_hwc<<<tgrid, 256, 0, stream>>>(features, ft);
        dim3 mgrid(HOUT, N);
        roialign_main<<<mgrid, 64, 0, stream>>>(ft, rois, out);
    } else {
        int total = N * CCH * SPP;
        roialign_fallback<<<(total + 255) / 256, 256, 0, stream>>>(features, rois, out, total);
    }
}

// Round 3
// 138.510 us; speedup vs baseline: 1.6592x; 1.1042x over previous
//
#include <hip/hip_runtime.h>

// ROIAlign: features (1, 256, 200, 200) f32, rois (N,4) f32 (y1,x1,y2,x2),
// img_size constant [800, 800]. Output (N, 256, 7, 7) f32.
//
// Pipeline:
//  1) transpose_v2: (C,H,W) -> (H,W,C) in d_ws. One block = all 256 channels
//     x 64 w at fixed h, via a 64 KB XOR-swizzled LDS tile. Reads are float4
//     coalesced; writes are full-wave 1 KB lines, each written exactly once.
//  2) roialign_main2: one block per ROI, 448 threads = 7 waves (wave q -> ho=q).
//     Each lane handles 4 contiguous channels (float4 taps). Results staged in
//     swizzled LDS then written out as fully-coalesced float4 stores.

#define CCH 256
#define HF 200
#define WF 200
#define HOUT 7
#define WOUT 7
#define SPP 49

// ---------------- transpose (C,H,W) -> (H,W,C) ----------------
// grid: (HF, ceil(WF/64)); block: 512 threads; LDS 64 KB.
// tile layout: row = local w (64 rows), 256 dwords per row; channel c stored at
// dword slot4*4 + (c&3), slot4 = (c>>2) ^ (w_local>>2). This makes:
//  - phase-1 scatter writes 2-way bank (free)
//  - phase-2 b128 reads conflict-free (slot = lane ^ (w>>2) permutes 16-groups)
__global__ __launch_bounds__(512) void transpose_v2(
    const float* __restrict__ f,   // (C, H, W)
    float* __restrict__ ft)        // (H, W, C)
{
    __shared__ float tile[64 * 256];   // 64 KB
    int h     = blockIdx.x;
    int wg    = blockIdx.y;
    int wbase = wg * 64;
    int t = threadIdx.x;
    int v  = t & 15;    // float4 index along w  (w_local = 4v..4v+3)
    int cu = t >> 4;    // 0..31

    #pragma unroll
    for (int pass = 0; pass < 8; ++pass) {
        int c  = pass * 32 + cu;
        int w0 = wbase + 4 * v;
        float4 val = make_float4(0.f, 0.f, 0.f, 0.f);
        if (w0 + 3 < WF) {   // wg=3: only v<2 valid (w 192..199); rest zero-fill
            val = *(const float4*)&f[(size_t)c * (HF * WF) + (size_t)h * WF + w0];
        }
        float vv[4] = {val.x, val.y, val.z, val.w};
        #pragma unroll
        for (int j = 0; j < 4; ++j) {
            int wl   = 4 * v + j;
            int slot = (c >> 2) ^ (wl >> 2);      // = (c>>2) ^ v
            tile[wl * 256 + slot * 4 + (c & 3)] = vv[j];
        }
    }
    __syncthreads();

    int l    = t & 63;
    int wave = t >> 6;   // 0..7
    #pragma unroll
    for (int pass = 0; pass < 8; ++pass) {
        int wl   = pass * 8 + wave;
        int w    = wbase + wl;
        int slot = l ^ (wl >> 2);                 // channel group l lives here
        float4 val = *(const float4*)&tile[wl * 256 + slot * 4];
        if (w < WF) {
            *(float4*)&ft[((size_t)h * WF + w) * CCH + 4 * l] = val;   // 1 KB/wave, full line
        }
    }
}

// ---------------- main: block = roi, 448 threads (wave q -> ho=q) -------------
__global__ __launch_bounds__(448) void roialign_main2(
    const float* __restrict__ ft,    // (H, W, C)
    const float* __restrict__ rois,  // (N, 4)
    float* __restrict__ out)         // (N, C, 7, 7)
{
    __shared__ float smem[CCH * 64];  // 64 KB; element (c,s) at c*64 + (s ^ ((c>>2)&31))
    int n = blockIdx.x;
    int t = threadIdx.x;
    int q = t >> 6;        // wave -> ho (0..6)
    int l = t & 63;
    int c4 = l * 4;

    float r0 = (rois[n * 4 + 0] * 199.0f) / 799.0f;
    float r1 = (rois[n * 4 + 1] * 199.0f) / 799.0f;
    float r2 = (rois[n * 4 + 2] * 199.0f) / 799.0f;
    float r3 = (rois[n * 4 + 3] * 199.0f) / 799.0f;
    float h_step = (r2 - r0) / 14.0f;
    float w_step = (r3 - r1) / 14.0f;

    int ho = q;

    float accx[WOUT], accy[WOUT], accz[WOUT], accw[WOUT];
    #pragma unroll
    for (int wo = 0; wo < WOUT; ++wo) {
        accx[wo] = -INFINITY; accy[wo] = -INFINITY;
        accz[wo] = -INFINITY; accw[wo] = -INFINITY;
    }

    #pragma unroll
    for (int a = 0; a < 2; ++a) {
        float yy = ((float)(2 * ho + a) + 0.5f) * h_step + r0;
        float yf = floorf(yy);
        int   iu = (int)yf;
        int   id = (int)ceilf(yy);    // ceil (matches ref; in-bounds by construction)
        float fy = yy - yf;

        const float* rowu = ft + (size_t)iu * (WF * CCH);
        const float* rowd = ft + (size_t)id * (WF * CCH);

        #pragma unroll
        for (int wo = 0; wo < WOUT; ++wo) {
            #pragma unroll
            for (int b = 0; b < 2; ++b) {
                float xx = ((float)(2 * wo + b) + 0.5f) * w_step + r1;
                float xf = floorf(xx);
                int   il = (int)xf;
                int   ir = (int)ceilf(xx);
                float fx = xx - xf;

                const float4 ul = *(const float4*)(rowu + (size_t)il * CCH + c4);
                const float4 ur = *(const float4*)(rowu + (size_t)ir * CCH + c4);
                const float4 dl = *(const float4*)(rowd + (size_t)il * CCH + c4);
                const float4 dr = *(const float4*)(rowd + (size_t)ir * CCH + c4);

                float w_ul = (1.0f - fy) * (1.0f - fx);
                float w_dl = fy * (1.0f - fx);
                float w_ur = (1.0f - fy) * fx;
                float w_dr = fy * fx;

                float vx = ul.x * w_ul + dl.x * w_dl + ur.x * w_ur + dr.x * w_dr;
                float vy = ul.y * w_ul + dl.y * w_dl + ur.y * w_ur + dr.y * w_dr;
                float vz = ul.z * w_ul + dl.z * w_dl + ur.z * w_ur + dr.z * w_dr;
                float vw = ul.w * w_ul + dl.w * w_dl + ur.w * w_ur + dr.w * w_dr;

                accx[wo] = fmaxf(accx[wo], vx);
                accy[wo] = fmaxf(accy[wo], vy);
                accz[wo] = fmaxf(accz[wo], vz);
                accw[wo] = fmaxf(accw[wo], vw);
            }
        }
    }

    // stage into swizzled LDS (col = s ^ (l&31); same col for the 4 c-rows)
    int swz = l & 31;
    #pragma unroll
    for (int wo = 0; wo < WOUT; ++wo) {
        int s   = ho * WOUT + wo;
        int col = s ^ swz;
        smem[(c4 + 0) * 64 + col] = accx[wo];
        smem[(c4 + 1) * 64 + col] = accy[wo];
        smem[(c4 + 2) * 64 + col] = accz[wo];
        smem[(c4 + 3) * 64 + col] = accw[wo];
    }
    __syncthreads();

    // coalesced copy-out: 12544 floats = 3136 float4 = 7 passes x 448 threads
    size_t outbase = (size_t)n * (CCH * SPP);
    #pragma unroll
    for (int p = 0; p < 7; ++p) {
        int o4 = p * 448 + t;
        int o  = o4 * 4;
        float tmp[4];
        #pragma unroll
        for (int i = 0; i < 4; ++i) {
            int oe = o + i;
            int c  = (int)((unsigned)oe / 49u);   // compiler magic-mul
            int s  = oe - c * 49;
            tmp[i] = smem[c * 64 + (s ^ ((c >> 2) & 31))];
        }
        float4 r;
        r.x = tmp[0]; r.y = tmp[1]; r.z = tmp[2]; r.w = tmp[3];
        *(float4*)&out[outbase + o] = r;
    }
}

// ---------------- fallback (no workspace) ----------------
__global__ __launch_bounds__(256) void roialign_fallback(
    const float* __restrict__ features,
    const float* __restrict__ rois,
    float* __restrict__ out,
    int total)
{
    int idx = blockIdx.x * blockDim.x + threadIdx.x;
    if (idx >= total) return;

    int s  = idx % SPP;
    int nc = idx / SPP;
    int c  = nc % CCH;
    int n  = nc / CCH;
    int ho = s / WOUT;
    int wo = s % WOUT;

    float r0 = (rois[n * 4 + 0] * 199.0f) / 799.0f;
    float r1 = (rois[n * 4 + 1] * 199.0f) / 799.0f;
    float r2 = (rois[n * 4 + 2] * 199.0f) / 799.0f;
    float r3 = (rois[n * 4 + 3] * 199.0f) / 799.0f;
    float h_step = (r2 - r0) / 14.0f;
    float w_step = (r3 - r1) / 14.0f;

    const float* fmap = features + (size_t)c * (HF * WF);
    float result = -INFINITY;

    #pragma unroll
    for (int a = 0; a < 2; ++a) {
        float yy = ((float)(2 * ho + a) + 0.5f) * h_step + r0;
        float yf = floorf(yy);
        int   iu = (int)yf;
        int   id = (int)ceilf(yy);
        float fy = yy - yf;
        const float* rowu = fmap + (size_t)iu * WF;
        const float* rowd = fmap + (size_t)id * WF;
        #pragma unroll
        for (int b = 0; b < 2; ++b) {
            float xx = ((float)(2 * wo + b) + 0.5f) * w_step + r1;
            float xf = floorf(xx);
            int   il = (int)xf;
            int   ir = (int)ceilf(xx);
            float fx = xx - xf;
            float val = rowu[il] * (1.0f - fy) * (1.0f - fx)
                      + rowd[il] * fy         * (1.0f - fx)
                      + rowu[ir] * (1.0f - fy) * fx
                      + rowd[ir] * fy         * fx;
            result = fmaxf(result, val);
        }
    }
    out[idx] = result;
}

extern "C" void kernel_launch(void* const* d_in, const int* in_sizes, int n_in,
                              void* d_out, int out_size, void* d_ws, size_t ws_size,
                              hipStream_t stream) {
    const float* features = (const float*)d_in[0];  // (1, 256, 200, 200)
    const float* rois     = (const float*)d_in[1];  // (N, 4)
    float* out = (float*)d_out;
    int N = in_sizes[1] / 4;

    const size_t need = (size_t)HF * WF * CCH * sizeof(float);  // 41 MB
    if (ws_size >= need) {
        float* ft = (float*)d_ws;
        dim3 tgrid(HF, (WF + 63) / 64);
        transpose_v2<<<tgrid, 512, 0, stream>>>(features, ft);
        roialign_main2<<<N, 448, 0, stream>>>(ft, rois, out);
    } else {
        int total = N * CCH * SPP;
        roialign_fallback<<<(total + 255) / 256, 256, 0, stream>>>(features, rois, out, total);
    }
}

// Round 4
// 132.695 us; speedup vs baseline: 1.7319x; 1.0438x over previous
//
#include <hip/hip_runtime.h>

// ROIAlign: features (1, 256, 200, 200) f32, rois (N,4) f32 (y1,x1,y2,x2),
// img_size constant [800, 800]. Output (N, 256, 7, 7) f32.
//
// Pipeline:
//  1) transpose_v2: (C,H,W) -> (H,W,C) in d_ws (unchanged from round 3).
//  2) roialign_main3: block = (roi, channel-half). 448 threads = 7 waves,
//     wave q -> ho=q; lanes 0-31 -> subsample a=0, lanes 32-63 -> a=1
//     (merged via shfl_xor(32)). Each lane: 4 contiguous channels (float4 taps).
//     LDS staging laid out exactly like the output slice -> trivially coalesced
//     flush. 24.5 KB LDS + VGPR<=73 -> 4 blocks/CU = 28 waves/CU.

#define CCH 256
#define HF 200
#define WF 200
#define HOUT 7
#define WOUT 7
#define SPP 49

// ---------------- transpose (C,H,W) -> (H,W,C) ----------------
__global__ __launch_bounds__(512) void transpose_v2(
    const float* __restrict__ f,   // (C, H, W)
    float* __restrict__ ft)        // (H, W, C)
{
    __shared__ float tile[64 * 256];   // 64 KB
    int h     = blockIdx.x;
    int wg    = blockIdx.y;
    int wbase = wg * 64;
    int t = threadIdx.x;
    int v  = t & 15;    // float4 index along w
    int cu = t >> 4;    // 0..31

    #pragma unroll
    for (int pass = 0; pass < 8; ++pass) {
        int c  = pass * 32 + cu;
        int w0 = wbase + 4 * v;
        float4 val = make_float4(0.f, 0.f, 0.f, 0.f);
        if (w0 + 3 < WF) {
            val = *(const float4*)&f[(size_t)c * (HF * WF) + (size_t)h * WF + w0];
        }
        float vv[4] = {val.x, val.y, val.z, val.w};
        #pragma unroll
        for (int j = 0; j < 4; ++j) {
            int wl   = 4 * v + j;
            int slot = (c >> 2) ^ (wl >> 2);
            tile[wl * 256 + slot * 4 + (c & 3)] = vv[j];
        }
    }
    __syncthreads();

    int l    = t & 63;
    int wave = t >> 6;
    #pragma unroll
    for (int pass = 0; pass < 8; ++pass) {
        int wl   = pass * 8 + wave;
        int w    = wbase + wl;
        int slot = l ^ (wl >> 2);
        float4 val = *(const float4*)&tile[wl * 256 + slot * 4];
        if (w < WF) {
            *(float4*)&ft[((size_t)h * WF + w) * CCH + 4 * l] = val;
        }
    }
}

// ---------------- main v3: block = (roi, channel-half) ----------------
__global__ __launch_bounds__(448, 7) void roialign_main3(
    const float* __restrict__ ft,    // (H, W, C)
    const float* __restrict__ rois,  // (N, 4)
    float* __restrict__ out)         // (N, C, 7, 7)
{
    __shared__ float smem[128 * SPP];   // 24.5 KB, laid out = output slice
    int n     = blockIdx.x;
    int chalf = blockIdx.y;
    int t  = threadIdx.x;
    int q  = t >> 6;        // wave -> ho (0..6)
    int l  = t & 63;
    int al = l >> 5;        // lane half -> subsample a (0/1)
    int lc = l & 31;        // channel lane
    int cg = chalf * 128 + lc * 4;   // global channel base

    float r0 = (rois[n * 4 + 0] * 199.0f) / 799.0f;
    float r1 = (rois[n * 4 + 1] * 199.0f) / 799.0f;
    float r2 = (rois[n * 4 + 2] * 199.0f) / 799.0f;
    float r3 = (rois[n * 4 + 3] * 199.0f) / 799.0f;
    float h_step = (r2 - r0) / 14.0f;
    float w_step = (r3 - r1) / 14.0f;

    // this lane's y row (ho = q, subsample a = al)
    float yy = ((float)(2 * q + al) + 0.5f) * h_step + r0;
    float yf = floorf(yy);
    int   iu = (int)yf;
    int   id = (int)ceilf(yy);     // ceil, matches ref
    float fy = yy - yf;

    const float* rowu = ft + (size_t)iu * (WF * CCH) + cg;
    const float* rowd = ft + (size_t)id * (WF * CCH) + cg;

    #pragma unroll 1
    for (int wo = 0; wo < WOUT; ++wo) {
        float mx = -INFINITY, my = -INFINITY, mz = -INFINITY, mw = -INFINITY;

        #pragma unroll
        for (int b = 0; b < 2; ++b) {
            float xx = ((float)(2 * wo + b) + 0.5f) * w_step + r1;
            float xf = floorf(xx);
            int   il = (int)xf;
            int   ir = (int)ceilf(xx);
            float fx = xx - xf;

            const float4 ul = *(const float4*)(rowu + (size_t)il * CCH);
            const float4 ur = *(const float4*)(rowu + (size_t)ir * CCH);
            const float4 dl = *(const float4*)(rowd + (size_t)il * CCH);
            const float4 dr = *(const float4*)(rowd + (size_t)ir * CCH);

            float w_ul = (1.0f - fy) * (1.0f - fx);
            float w_dl = fy * (1.0f - fx);
            float w_ur = (1.0f - fy) * fx;
            float w_dr = fy * fx;

            mx = fmaxf(mx, ul.x * w_ul + dl.x * w_dl + ur.x * w_ur + dr.x * w_dr);
            my = fmaxf(my, ul.y * w_ul + dl.y * w_dl + ur.y * w_ur + dr.y * w_dr);
            mz = fmaxf(mz, ul.z * w_ul + dl.z * w_dl + ur.z * w_ur + dr.z * w_dr);
            mw = fmaxf(mw, ul.w * w_ul + dl.w * w_dl + ur.w * w_ur + dr.w * w_dr);
        }

        // merge the two subsample-a halves (lanes l and l^32 hold same channels)
        mx = fmaxf(mx, __shfl_xor(mx, 32));
        my = fmaxf(my, __shfl_xor(my, 32));
        mz = fmaxf(mz, __shfl_xor(mz, 32));
        mw = fmaxf(mw, __shfl_xor(mw, 32));

        if (al == 0) {
            int s  = q * WOUT + wo;
            int cb = lc * 4;
            smem[(cb + 0) * SPP + s] = mx;
            smem[(cb + 1) * SPP + s] = my;
            smem[(cb + 2) * SPP + s] = mz;
            smem[(cb + 3) * SPP + s] = mw;
        }
    }
    __syncthreads();

    // flush: 128*49 = 6272 floats = 1568 float4, contiguous in out
    float* dst = out + (size_t)n * (CCH * SPP) + chalf * (128 * SPP);
    #pragma unroll
    for (int p = 0; p < 4; ++p) {
        int o4 = p * 448 + t;
        if (o4 < 1568) {
            float4 v = *(const float4*)&smem[o4 * 4];
            *(float4*)&dst[o4 * 4] = v;
        }
    }
}

// ---------------- fallback (no workspace) ----------------
__global__ __launch_bounds__(256) void roialign_fallback(
    const float* __restrict__ features,
    const float* __restrict__ rois,
    float* __restrict__ out,
    int total)
{
    int idx = blockIdx.x * blockDim.x + threadIdx.x;
    if (idx >= total) return;

    int s  = idx % SPP;
    int nc = idx / SPP;
    int c  = nc % CCH;
    int n  = nc / CCH;
    int ho = s / WOUT;
    int wo = s % WOUT;

    float r0 = (rois[n * 4 + 0] * 199.0f) / 799.0f;
    float r1 = (rois[n * 4 + 1] * 199.0f) / 799.0f;
    float r2 = (rois[n * 4 + 2] * 199.0f) / 799.0f;
    float r3 = (rois[n * 4 + 3] * 199.0f) / 799.0f;
    float h_step = (r2 - r0) / 14.0f;
    float w_step = (r3 - r1) / 14.0f;

    const float* fmap = features + (size_t)c * (HF * WF);
    float result = -INFINITY;

    #pragma unroll
    for (int a = 0; a < 2; ++a) {
        float yy = ((float)(2 * ho + a) + 0.5f) * h_step + r0;
        float yf = floorf(yy);
        int   iu = (int)yf;
        int   id = (int)ceilf(yy);
        float fy = yy - yf;
        const float* rowu = fmap + (size_t)iu * WF;
        const float* rowd = fmap + (size_t)id * WF;
        #pragma unroll
        for (int b = 0; b < 2; ++b) {
            float xx = ((float)(2 * wo + b) + 0.5f) * w_step + r1;
            float xf = floorf(xx);
            int   il = (int)xf;
            int   ir = (int)ceilf(xx);
            float fx = xx - xf;
            float val = rowu[il] * (1.0f - fy) * (1.0f - fx)
                      + rowd[il] * fy         * (1.0f - fx)
                      + rowu[ir] * (1.0f - fy) * fx
                      + rowd[ir] * fy         * fx;
            result = fmaxf(result, val);
        }
    }
    out[idx] = result;
}

extern "C" void kernel_launch(void* const* d_in, const int* in_sizes, int n_in,
                              void* d_out, int out_size, void* d_ws, size_t ws_size,
                              hipStream_t stream) {
    const float* features = (const float*)d_in[0];  // (1, 256, 200, 200)
    const float* rois     = (const float*)d_in[1];  // (N, 4)
    float* out = (float*)d_out;
    int N = in_sizes[1] / 4;

    const size_t need = (size_t)HF * WF * CCH * sizeof(float);  // 41 MB
    if (ws_size >= need) {
        float* ft = (float*)d_ws;
        dim3 tgrid(HF, (WF + 63) / 64);
        transpose_v2<<<tgrid, 512, 0, stream>>>(features, ft);
        dim3 mgrid(N, 2);
        roialign_main3<<<mgrid, 448, 0, stream>>>(ft, rois, out);
    } else {
        int total = N * CCH * SPP;
        roialign_fallback<<<(total + 255) / 256, 256, 0, stream>>>(features, rois, out, total);
    }
}

// Round 5
// 110.717 us; speedup vs baseline: 2.0757x; 1.1985x over previous
//
#include <hip/hip_runtime.h>

// ROIAlign: features (1, 256, 200, 200) f32, rois (N,4) f32 (y1,x1,y2,x2),
// img_size constant [800, 800]. Output (N, 256, 7, 7) f32.
//
// All measured configs pin at ~3.5 TB/s effective HBM-side BW -> traffic-bound.
// Round 5: store the transposed (H,W,C) map as bf16 (RNE) -> halves map bytes
// (41 -> 20.5 MB) and halves refetch pressure on the 4 MB/XCD L2. One 16 B
// lane-load now covers 8 channels, so one block = one ROI covers all 256 ch.

#define CCH 256
#define HF 200
#define WF 200
#define HOUT 7
#define WOUT 7
#define SPP 49
#define SPPP 50   // padded LDS stride (2-way banks = free)

__device__ __forceinline__ unsigned short f2bf_rne(float x) {
    unsigned int u = __float_as_uint(x);
    unsigned int r = (u + 0x7fffu + ((u >> 16) & 1u)) >> 16;
    return (unsigned short)r;
}
__device__ __forceinline__ float bf_lo(unsigned int u) { return __uint_as_float(u << 16); }
__device__ __forceinline__ float bf_hi(unsigned int u) { return __uint_as_float(u & 0xffff0000u); }

// ---------------- transpose+quantize (C,H,W) f32 -> (H,W,C) bf16 -------------
// grid: (HF, 4); block 512; LDS 32 KB ushort tile[64][256], columns XOR-swizzled
// by k = (wl>>2)&7 (c' = c ^ (k<<3)) to break the 512 B row-stride bank pattern.
__global__ __launch_bounds__(512) void transpose_bf16(
    const float* __restrict__ f,          // (C, H, W) f32
    unsigned short* __restrict__ ft)      // (H, W, C) bf16
{
    __shared__ unsigned short tile[64 * 256];   // 32 KB
    int h     = blockIdx.x;
    int wg    = blockIdx.y;
    int wbase = wg * 64;
    int t = threadIdx.x;
    int v  = t & 15;    // float4 index along w
    int cu = t >> 4;    // 0..31

    #pragma unroll
    for (int pass = 0; pass < 8; ++pass) {
        int c  = pass * 32 + cu;
        int w0 = wbase + 4 * v;
        if (w0 < WF) {   // WF%4==0 so full float4 when valid
            float4 val = *(const float4*)&f[(size_t)c * (HF * WF) + (size_t)h * WF + w0];
            float vv[4] = {val.x, val.y, val.z, val.w};
            #pragma unroll
            for (int j = 0; j < 4; ++j) {
                int wl = 4 * v + j;
                int k  = (wl >> 2) & 7;           // = v & 7
                tile[wl * 256 + (c ^ (k << 3))] = f2bf_rne(vv[j]);
            }
        }
    }
    __syncthreads();

    // write-out: 64 lanes x 16 B = 2 rows (512 B each) per wave-instr
    int l    = t & 63;
    int wave = t >> 6;   // 0..7
    int lc   = l & 31;
    #pragma unroll
    for (int p = 0; p < 4; ++p) {
        int wl = (p * 8 + wave) * 2 + (l >> 5);
        int w  = wbase + wl;
        int k  = (wl >> 2) & 7;
        int c8 = lc * 8;
        uint4 val = *(const uint4*)&tile[wl * 256 + (c8 ^ (k << 3))];
        if (w < WF) {
            *(uint4*)&ft[((size_t)h * WF + w) * CCH + c8] = val;
        }
    }
}

// ---------------- main v4: block = roi (all 256 channels) ----------------
// 448 threads = 7 waves, wave q -> ho; lanes 0-31 subsample a=0, 32-63 a=1
// (merged via shfl_xor(32)); each lane: 8 channels via one 16 B bf16 load/tap.
__global__ __launch_bounds__(448, 4) void roialign_main4(
    const unsigned short* __restrict__ ft,   // (H, W, C) bf16
    const float* __restrict__ rois,          // (N, 4)
    float* __restrict__ out)                 // (N, C, 7, 7)
{
    __shared__ float smem[CCH * SPPP];   // 51.2 KB; (c,s) at c*50+s
    int n  = blockIdx.x;
    int t  = threadIdx.x;
    int q  = t >> 6;        // wave -> ho
    int l  = t & 63;
    int al = l >> 5;        // subsample a
    int lc = l & 31;
    int c8 = lc * 8;        // channel base

    float r0 = (rois[n * 4 + 0] * 199.0f) / 799.0f;
    float r1 = (rois[n * 4 + 1] * 199.0f) / 799.0f;
    float r2 = (rois[n * 4 + 2] * 199.0f) / 799.0f;
    float r3 = (rois[n * 4 + 3] * 199.0f) / 799.0f;
    float h_step = (r2 - r0) / 14.0f;
    float w_step = (r3 - r1) / 14.0f;

    float yy = ((float)(2 * q + al) + 0.5f) * h_step + r0;
    float yf = floorf(yy);
    int   iu = (int)yf;
    int   id = (int)ceilf(yy);     // ceil, matches ref
    float fy = yy - yf;

    const unsigned short* rowu = ft + (size_t)iu * (WF * CCH) + c8;
    const unsigned short* rowd = ft + (size_t)id * (WF * CCH) + c8;

    #pragma unroll 1
    for (int wo = 0; wo < WOUT; ++wo) {
        float m[8];
        #pragma unroll
        for (int j = 0; j < 8; ++j) m[j] = -INFINITY;

        #pragma unroll
        for (int b = 0; b < 2; ++b) {
            float xx = ((float)(2 * wo + b) + 0.5f) * w_step + r1;
            float xf = floorf(xx);
            int   il = (int)xf;
            int   ir = (int)ceilf(xx);
            float fx = xx - xf;

            uint4 Uul = *(const uint4*)(rowu + (size_t)il * CCH);
            uint4 Uur = *(const uint4*)(rowu + (size_t)ir * CCH);
            uint4 Udl = *(const uint4*)(rowd + (size_t)il * CCH);
            uint4 Udr = *(const uint4*)(rowd + (size_t)ir * CCH);

            float w_ul = (1.0f - fy) * (1.0f - fx);
            float w_dl = fy * (1.0f - fx);
            float w_ur = (1.0f - fy) * fx;
            float w_dr = fy * fx;

            const unsigned int* pul = (const unsigned int*)&Uul;
            const unsigned int* pur = (const unsigned int*)&Uur;
            const unsigned int* pdl = (const unsigned int*)&Udl;
            const unsigned int* pdr = (const unsigned int*)&Udr;

            #pragma unroll
            for (int g = 0; g < 4; ++g) {
                float vlo = bf_lo(pul[g]) * w_ul + bf_lo(pdl[g]) * w_dl
                          + bf_lo(pur[g]) * w_ur + bf_lo(pdr[g]) * w_dr;
                float vhi = bf_hi(pul[g]) * w_ul + bf_hi(pdl[g]) * w_dl
                          + bf_hi(pur[g]) * w_ur + bf_hi(pdr[g]) * w_dr;
                m[2 * g + 0] = fmaxf(m[2 * g + 0], vlo);
                m[2 * g + 1] = fmaxf(m[2 * g + 1], vhi);
            }
        }

        // merge the two subsample-a halves (lanes l and l^32 hold same channels)
        #pragma unroll
        for (int j = 0; j < 8; ++j) m[j] = fmaxf(m[j], __shfl_xor(m[j], 32));

        if (al == 0) {
            int s = q * WOUT + wo;
            #pragma unroll
            for (int j = 0; j < 8; ++j) smem[(c8 + j) * SPPP + s] = m[j];
        }
    }
    __syncthreads();

    // flush: 256*49 = 12544 floats = 3136 float4, contiguous in out
    float* dst = out + (size_t)n * (CCH * SPP);
    #pragma unroll
    for (int p = 0; p < 7; ++p) {
        int o4 = p * 448 + t;
        int o  = o4 * 4;
        float tmp[4];
        #pragma unroll
        for (int i = 0; i < 4; ++i) {
            int oe = o + i;
            int c  = (int)((unsigned)oe / 49u);   // magic-mul
            int s  = oe - c * 49;
            tmp[i] = smem[c * SPPP + s];
        }
        float4 r;
        r.x = tmp[0]; r.y = tmp[1]; r.z = tmp[2]; r.w = tmp[3];
        *(float4*)&dst[o] = r;
    }
}

// ---------------- fallback (no workspace) ----------------
__global__ __launch_bounds__(256) void roialign_fallback(
    const float* __restrict__ features,
    const float* __restrict__ rois,
    float* __restrict__ out,
    int total)
{
    int idx = blockIdx.x * blockDim.x + threadIdx.x;
    if (idx >= total) return;

    int s  = idx % SPP;
    int nc = idx / SPP;
    int c  = nc % CCH;
    int n  = nc / CCH;
    int ho = s / WOUT;
    int wo = s % WOUT;

    float r0 = (rois[n * 4 + 0] * 199.0f) / 799.0f;
    float r1 = (rois[n * 4 + 1] * 199.0f) / 799.0f;
    float r2 = (rois[n * 4 + 2] * 199.0f) / 799.0f;
    float r3 = (rois[n * 4 + 3] * 199.0f) / 799.0f;
    float h_step = (r2 - r0) / 14.0f;
    float w_step = (r3 - r1) / 14.0f;

    const float* fmap = features + (size_t)c * (HF * WF);
    float result = -INFINITY;

    #pragma unroll
    for (int a = 0; a < 2; ++a) {
        float yy = ((float)(2 * ho + a) + 0.5f) * h_step + r0;
        float yf = floorf(yy);
        int   iu = (int)yf;
        int   id = (int)ceilf(yy);
        float fy = yy - yf;
        const float* rowu = fmap + (size_t)iu * WF;
        const float* rowd = fmap + (size_t)id * WF;
        #pragma unroll
        for (int b = 0; b < 2; ++b) {
            float xx = ((float)(2 * wo + b) + 0.5f) * w_step + r1;
            float xf = floorf(xx);
            int   il = (int)xf;
            int   ir = (int)ceilf(xx);
            float fx = xx - xf;
            float val = rowu[il] * (1.0f - fy) * (1.0f - fx)
                      + rowd[il] * fy         * (1.0f - fx)
                      + rowu[ir] * (1.0f - fy) * fx
                      + rowd[ir] * fy         * fx;
            result = fmaxf(result, val);
        }
    }
    out[idx] = result;
}

extern "C" void kernel_launch(void* const* d_in, const int* in_sizes, int n_in,
                              void* d_out, int out_size, void* d_ws, size_t ws_size,
                              hipStream_t stream) {
    const float* features = (const float*)d_in[0];  // (1, 256, 200, 200)
    const float* rois     = (const float*)d_in[1];  // (N, 4)
    float* out = (float*)d_out;
    int N = in_sizes[1] / 4;

    const size_t need = (size_t)HF * WF * CCH * sizeof(unsigned short);  // 20.5 MB
    if (ws_size >= need) {
        unsigned short* ft = (unsigned short*)d_ws;
        dim3 tgrid(HF, (WF + 63) / 64);
        transpose_bf16<<<tgrid, 512, 0, stream>>>(features, ft);
        roialign_main4<<<N, 448, 0, stream>>>(ft, rois, out);
    } else {
        int total = N * CCH * SPP;
        roialign_fallback<<<(total + 255) / 256, 256, 0, stream>>>(features, rois, out, total);
    }
}